// Round 11
// baseline (409.674 us; speedup 1.0000x reference)
//
#include <hip/hip_runtime.h>
#include <hip/hip_bf16.h>

#define DD 80
#define CIN 32
#define PLANE (DD*DD)        // 6400
#define VOX (DD*DD*DD)       // 512000
#define NPTS 200000

typedef __attribute__((ext_vector_type(8))) short bf16x8;
typedef __attribute__((ext_vector_type(4))) float floatx4;
typedef __attribute__((ext_vector_type(4))) short s4v;

static __device__ __forceinline__ short f2bf(float v) {
    __hip_bfloat16 b = __float2bfloat16(v);
    return *(short*)&b;
}

// async global->LDS 16B copy: lane's 16B lands at ldsbase + lane*16 (wave-uniform base);
// the GLOBAL source address is per-lane.
static __device__ __forceinline__ void async_copy16(void* lds, const void* g) {
    __builtin_amdgcn_global_load_lds(
        (const __attribute__((address_space(1))) unsigned int*)g,
        (__attribute__((address_space(3))) unsigned int*)lds, 16, 0, 0);
}

// ---------------- K0: convert/permute all weights to bf16 ----------------
// wpb: conv2 W fragment order [off][nt][ks][lane][e] (A/B-symmetric MFMA layout).
// w1f/w2f/w3f: MLP weights as MFMA A-operand fragments for transposed compute
// C'[n][m] = W x H^T: lane (q,lc) holds row n = base + lc, k = ks*32 + q*8 + e.
__global__ void convert_weights(const float* __restrict__ w2,
                                const float* __restrict__ w_p1,
                                const float* __restrict__ w_p2,
                                const float* __restrict__ w_p3,
                                const float* __restrict__ w_e1,
                                short* __restrict__ wpb, short* __restrict__ w1f,
                                short* __restrict__ w2f, short* __restrict__ w3f,
                                short* __restrict__ wc1) {
    int i = blockIdx.x * 256 + threadIdx.x;      // total 264192
    if (i < 110592) {
        int off = i >> 12, r = i & 4095;
        int nt = r >> 10, r2 = r & 1023;
        int ks = r2 >> 9, r3 = r2 & 511;
        int lane = r3 >> 3, e = r3 & 7;
        int oc = nt * 16 + (lane & 15);
        int ic = ks * 32 + (lane >> 4) * 8 + e;
        wpb[i] = f2bf(w2[oc * 1728 + ic * 27 + off]);
    } else if (i < 110592 + 16384) {
        int j = i - 110592;
        int frag = j >> 9, r3 = j & 511;
        int lane = r3 >> 3, e = r3 & 7;
        int ks = frag & 1, nt = (frag >> 1) & 3, w = frag >> 3;
        int n = w * 64 + nt * 16 + (lane & 15);
        int k = ks * 32 + (lane >> 4) * 8 + e;
        w1f[j] = f2bf(w_p1[n * 64 + k]);
    } else if (i < 110592 + 16384 + 65536) {
        int j = i - 110592 - 16384;
        int frag = j >> 9, r3 = j & 511;
        int lane = r3 >> 3, e = r3 & 7;
        int ks = frag & 7, nt = (frag >> 3) & 3, w = frag >> 5;
        int n = w * 64 + nt * 16 + (lane & 15);
        int k = ks * 32 + (lane >> 4) * 8 + e;
        w2f[j] = f2bf(w_p2[n * 256 + k]);
    } else if (i < 110592 + 16384 + 65536 + 16384) {
        int j = i - 110592 - 16384 - 65536;
        int frag = j >> 9, r3 = j & 511;
        int lane = r3 >> 3, e = r3 & 7;
        int ks = frag & 7, w = frag >> 3;
        int n = w * 16 + (lane & 15);
        int k = ks * 32 + (lane >> 4) * 8 + e;
        w3f[j] = f2bf(w_p3[n * 256 + k]);
    } else if (i < 110592 + 16384 + 65536 + 16384 + 55296) {
        int j = i - (110592 + 16384 + 65536 + 16384);   // [off][oc][ic]
        int off = j / 2048, r = j - off * 2048;
        int oc = r >> 5, ic = r & 31;
        wc1[j] = f2bf(w_e1[(oc * 32 + ic) * 27 + off]);
    }
}

// ---------------- K0b: transpose img (32,VOX) fp32 -> img_t [vox][32] bf16 ----------------
__global__ __launch_bounds__(256) void transpose_img(
    const float* __restrict__ img, short* __restrict__ img_t)
{
    int v = blockIdx.x * 256 + threadIdx.x;
    if (v >= VOX) return;
    short row[32];
    #pragma unroll
    for (int ic = 0; ic < 32; ic++)
        row[ic] = f2bf(img[(size_t)ic * VOX + v]);
    int4* dst = (int4*)(img_t + (size_t)v * 32);
    #pragma unroll
    for (int c = 0; c < 4; c++) dst[c] = ((int4*)row)[c];
}

// ---------------- K1: conv1 via implicit-GEMM MFMA (round-10 tuned) ----------------
__global__ __launch_bounds__(256) void conv1_mfma(
    const short* __restrict__ img_t, const short* __restrict__ wc1,
    const float* __restrict__ b1, const short* __restrict__ zeros,
    short* __restrict__ f1)
{
    __shared__ short Alds[3072 * 16 / 2];   // 48 KB

    const int bh = blockIdx.x;
    const int d = bh / DD, h = bh - d * DD;
    const int tid = threadIdx.x;
    const int w = tid >> 6, lane = tid & 63;
    const int q = lane >> 4, lc = lane & 15;

    for (int i = 0; i < 12; i++) {
        int s = (w * 12 + i) * 64 + lane;      // slot 0..3071
        int row = s >> 2, c = s & 3;
        int cs = c ^ ((row >> 1) & 3);         // swizzled source chunk (mod-8 spread)
        int rr = row / 82, v = row - rr * 82;
        int dz = rr / 3, dyy = rr - dz * 3;
        int zz = d + dz - 1, yy = h + dyy - 1, ww = v - 1;
        const short* src = zeros;
        if (row < 738 && (unsigned)zz < DD && (unsigned)yy < DD && (unsigned)ww < DD)
            src = img_t + ((size_t)(zz * PLANE + yy * DD + ww)) * 32 + cs * 8;
        async_copy16(&Alds[(w * 12 + i) * 512], src);
    }
    __syncthreads();

    floatx4 acc[5];
    #pragma unroll
    for (int mt = 0; mt < 5; mt++) acc[mt] = (floatx4){0.f, 0.f, 0.f, 0.f};

    for (int dz = 0; dz < 3; dz++) {
        for (int dy = 0; dy < 3; dy++) {
            const int rr = dz * 3 + dy;
            #pragma unroll
            for (int dx = 0; dx < 3; dx++) {
                const int off = rr * 3 + dx;
                bf16x8 bfr = *(const bf16x8*)(wc1 + ((off * 64 + w * 16 + lc) << 5) + q * 8);
                #pragma unroll
                for (int mt = 0; mt < 5; mt++) {
                    const int vv = rr * 82 + mt * 16 + lc + dx;
                    bf16x8 afr = *(const bf16x8*)(
                        &Alds[vv * 32 + ((q ^ ((vv >> 1) & 3)) << 3)]);
                    acc[mt] = __builtin_amdgcn_mfma_f32_16x16x32_bf16(afr, bfr, acc[mt], 0, 0, 0);
                }
            }
        }
    }

    const int oc = w * 16 + lc;
    const float bias = b1[oc];
    const size_t vbase = (size_t)(d * DD + h) * DD;
    #pragma unroll
    for (int mt = 0; mt < 5; mt++) {
        #pragma unroll
        for (int r = 0; r < 4; r++) {
            const int m = mt * 16 + q * 4 + r;
            float v = acc[mt][r] + bias;
            f1[(vbase + m) * 64 + oc] = f2bf(v > 0.f ? v : 0.f);
        }
    }
}

// ---------------- binning v3: LDS-histogram counting sort, [cell][block] partials ----------------
#define NSB 32   // sort blocks

__global__ __launch_bounds__(512) void hist_cells(
    const int* __restrict__ c0, const int* __restrict__ c1, const int* __restrict__ c2,
    int* __restrict__ partial)
{
    __shared__ int h[1000];
    const int tid = threadIdx.x;
    for (int c = tid; c < 1000; c += 512) h[c] = 0;
    __syncthreads();
    for (int p = blockIdx.x * 512 + tid; p < NPTS; p += NSB * 512) {
        int cell = (c0[p] >> 3) * 100 + (c1[p] >> 3) * 10 + (c2[p] >> 3);
        atomicAdd(&h[cell], 1);
    }
    __syncthreads();
    for (int c = tid; c < 1000; c += 512) partial[c * NSB + blockIdx.x] = h[c];
}

__global__ __launch_bounds__(1024) void scan_cells(
    const int* __restrict__ partial, int* __restrict__ blockbase,
    int* __restrict__ cs, int* __restrict__ ce)
{
    __shared__ int a[1024], b[1024];
    const int t = threadIdx.x;
    int sum = 0;
    if (t < 1000) {
        const int base = t * NSB;                    // contiguous 32-int run per cell
        int run = 0;
        #pragma unroll 8
        for (int bb = 0; bb < NSB; bb++) {
            blockbase[base + bb] = run;              // exclusive within-cell prefix
            run += partial[base + bb];
        }
        sum = run;
    }
    a[t] = sum;
    __syncthreads();
    int* src = a; int* dst = b;
    for (int d = 1; d < 1024; d <<= 1) {
        int v = src[t];
        if (t >= d) v += src[t - d];
        dst[t] = v;
        __syncthreads();
        int* tmp = src; src = dst; dst = tmp;
    }
    if (t < 1000) { cs[t] = src[t] - sum; ce[t] = src[t]; }
}

__global__ __launch_bounds__(512) void scatter_points(
    const int* __restrict__ c0, const int* __restrict__ c1, const int* __restrict__ c2,
    const int* __restrict__ cs, const int* __restrict__ blockbase,
    int* __restrict__ perm, int* __restrict__ pcoord)
{
    __shared__ int cur[1000];
    const int tid = threadIdx.x;
    for (int c = tid; c < 1000; c += 512) cur[c] = 0;
    __syncthreads();
    for (int p = blockIdx.x * 512 + tid; p < NPTS; p += NSB * 512) {
        int z = c0[p], y = c1[p], x = c2[p];
        int cell = (z >> 3) * 100 + (y >> 3) * 10 + (x >> 3);
        int r = atomicAdd(&cur[cell], 1);            // LDS atomic
        int pos = cs[cell] + blockbase[cell * NSB + blockIdx.x] + r;
        perm[pos] = p;
        pcoord[pos] = z | (y << 8) | (x << 16);
    }
}

// ---------------- K2: FUSED conv2 + MLP per cell block ----------------
// Conv phase: round-8/10 cell-halo structure but with SWAPPED MFMA operands
// (mfma(W, X) -- A/B lane layouts are symmetric, so no gather/weight changes):
// acc = C[oc-rows][pt-cols], making the epilogue packed 8 B stores straight into
// the MLP's Xls LDS format (2-way bank-free via the chunk swizzle).
// MLP phase: round-9 transposed layers run in-block on 4 x 64-point groups
// (8-wave N-split, nidx = 2w+j), reusing the dead halo LDS for X/H1/H2.
// Eliminates the 26 MB g round-trip AND the separate mlp launch; MLP MFMAs fill
// the conv kernel's 74%-idle matrix pipe. Bit-identical numerics to the split path.
__global__ __launch_bounds__(512) void conv2_mlp_fused(
    const short* __restrict__ f1s, const short* __restrict__ wfb,
    const float* __restrict__ b2,
    const int* __restrict__ cs, const int* __restrict__ ce,
    const int* __restrict__ perm, const int* __restrict__ pcoord,
    const short* __restrict__ zeros,
    const short* __restrict__ w1f, const float* __restrict__ bp1,
    const short* __restrict__ w2f, const float* __restrict__ bp2,
    const short* __restrict__ w3f, const float* __restrict__ bp3,
    const float* __restrict__ wp4, const float* __restrict__ bp4,
    float* __restrict__ out)
{
    __shared__ short U[64000];          // 128000 B union: halo | {Xg[4] | H1 | H2}
    short* Alds = U;                    // 125 KB halo: row r, slot s holds chunk s^(r&7)
    short* Xg = U;                      // 4 x [64][64] bf16, chunk-swizzled (32 KB)
    short* H1 = U + 16384;              // [64][256] bf16 (32 KB)
    short* H2 = U + 32768;              // [64][256] bf16 (32 KB)
    float* h3f = (float*)H1;            // fp32 [64][68] overlay (H1 free after L2)

    // bijective XCD swizzle (1000 = 8*125)
    int bid = blockIdx.x;
    { const int xcd = bid & 7, i = bid >> 3; bid = xcd * 125 + i; }
    const int cell = bid;
    const int cz = cell / 100, cyx = cell - cz * 100;
    const int cy = cyx / 10, cx = cyx - cy * 10;

    const int tid = threadIdx.x;
    const int w = tid >> 6, lane = tid & 63;
    const int q = lane >> 4, lc = lane & 15;

    const int pstart = cs[cell], pend = ce[cell];
    const int pr = lane >> 3, pcs = lane & 7, ccs = pcs ^ pr;
    const int gz0 = cz * 8 - 1, gy0 = cy * 8 - 1, gx0 = cx * 8 - 1;

    for (int pb2 = pstart; pb2 < pend; pb2 += 256) {
        // ---- halo load (once for ~all cells; reloaded only for rare >256-pt cells) ----
        for (int j = w; j < 125; j += 8) {
            int r = j * 8 + pr;
            int hz = r / 100; int rem = r - hz * 100;
            int hy = rem / 10; int hx = rem - hy * 10;
            int gz = gz0 + hz, gy = gy0 + hy, gx = gx0 + hx;
            const short* src = zeros + ccs * 8;
            if ((unsigned)gz < DD && (unsigned)gy < DD && (unsigned)gx < DD)
                src = f1s + (size_t)(gz * PLANE + gy * DD + gx) * 64 + ccs * 8;
            async_copy16(&Alds[j * 512], src);
        }
        asm volatile("s_waitcnt vmcnt(0)" ::: "memory");
        __syncthreads();

        // ---- conv phase: acc[mt][nt] = C[oc = nt*16+q*4+r][pt = pb2+w*32+mt*16+lc] ----
        int hbase[2];
        #pragma unroll
        for (int mt = 0; mt < 2; mt++) {
            int p = pb2 + w * 32 + mt * 16 + lc;
            if (p >= pend) p = pend - 1;
            int pk = pcoord[p];
            int z = pk & 0xff, y = (pk >> 8) & 0xff, x = (pk >> 16) & 0xff;
            hbase[mt] = (z - gz0) * 100 + (y - gy0) * 10 + (x - gx0);
        }

        floatx4 acc[2][4];
        #pragma unroll
        for (int mt = 0; mt < 2; mt++)
            #pragma unroll
            for (int nt = 0; nt < 4; nt++)
                acc[mt][nt] = (floatx4){0.f, 0.f, 0.f, 0.f};

        if (pb2 + w * 32 < pend) {          // wave-uniform: skip fully-padded waves
            for (int dz = 0; dz < 3; dz++) {
                for (int dy = 0; dy < 3; dy++) {
                    const int rowoff = (dz - 1) * 100 + (dy - 1) * 10;
                    const int offbase = (dz * 3 + dy) * 3;
                    #pragma unroll
                    for (int dx = 0; dx < 3; dx++) {
                        const int off = offbase + dx;
                        const int dh = rowoff + dx - 1;

                        bf16x8 bfr[4][2];
                        #pragma unroll
                        for (int nt = 0; nt < 4; nt++)
                            #pragma unroll
                            for (int ks = 0; ks < 2; ks++)
                                bfr[nt][ks] = *(const bf16x8*)(
                                    wfb + off * 4096 + nt * 1024 + ks * 512 + lane * 8);

                        bf16x8 afr[2][2];
                        #pragma unroll
                        for (int mt = 0; mt < 2; mt++) {
                            const int hrow = hbase[mt] + dh;
                            const int sw = hrow & 7;
                            #pragma unroll
                            for (int ks = 0; ks < 2; ks++)
                                afr[mt][ks] = *(const bf16x8*)(
                                    &Alds[hrow * 64 + (((ks * 4 + q) ^ sw) << 3)]);
                        }

                        #pragma unroll
                        for (int ks = 0; ks < 2; ks++)
                            #pragma unroll
                            for (int mt = 0; mt < 2; mt++)
                                #pragma unroll
                                for (int nt = 0; nt < 4; nt++)
                                    acc[mt][nt] = __builtin_amdgcn_mfma_f32_16x16x32_bf16(
                                        bfr[nt][ks], afr[mt][ks], acc[mt][nt], 0, 0, 0);
                    }
                }
            }
        }
        __syncthreads();   // all halo reads done before X overwrites the union region

        // ---- X-writes: g values straight into MLP Xls format (packed 8 B stores) ----
        {
            short* Xw = Xg + (w >> 1) * 4096;        // group = w>>1
            #pragma unroll
            for (int nt = 0; nt < 4; nt++) {
                const floatx4 bs = *(const floatx4*)(b2 + nt * 16 + q * 4);
                const int chunk = nt * 2 + (q >> 1);
                #pragma unroll
                for (int mt = 0; mt < 2; mt++) {
                    const int m = (w & 1) * 32 + mt * 16 + lc;
                    s4v hv;
                    #pragma unroll
                    for (int r = 0; r < 4; r++) {
                        float v = acc[mt][nt][r] + bs[r];
                        hv[r] = f2bf(v > 0.f ? v : 0.f);
                    }
                    *(s4v*)(&Xw[m * 64 + ((chunk ^ (m & 7)) << 3) + ((q & 1) << 2)]) = hv;
                }
            }
        }
        __syncthreads();

        // ---- MLP: 4 groups of 64 points, 8-wave N-split (nidx = 2w+j) ----
        for (int grp = 0; grp < 4; grp++) {
            if (pb2 + grp * 64 >= pend) break;       // block-uniform
            const short* Xls = Xg + grp * 4096;

            // L1: 64 -> 256, relu
            {
                floatx4 a1[4][2];
                #pragma unroll
                for (int mt = 0; mt < 4; mt++)
                    #pragma unroll
                    for (int j = 0; j < 2; j++)
                        a1[mt][j] = (floatx4){0.f, 0.f, 0.f, 0.f};

                #pragma unroll
                for (int ks = 0; ks < 2; ks++) {
                    bf16x8 wf[2];
                    #pragma unroll
                    for (int j = 0; j < 2; j++)
                        wf[j] = *(const bf16x8*)(w1f + (((2 * w + j) * 2 + ks) << 9) + lane * 8);
                    const int c = ks * 4 + q;
                    #pragma unroll
                    for (int mt = 0; mt < 4; mt++) {
                        const int m = mt * 16 + lc;
                        bf16x8 hf = *(const bf16x8*)(&Xls[m * 64 + ((c ^ (m & 7)) << 3)]);
                        #pragma unroll
                        for (int j = 0; j < 2; j++)
                            a1[mt][j] = __builtin_amdgcn_mfma_f32_16x16x32_bf16(wf[j], hf, a1[mt][j], 0, 0, 0);
                    }
                }
                #pragma unroll
                for (int j = 0; j < 2; j++) {
                    const int nidx = 2 * w + j;
                    const floatx4 bs = *(const floatx4*)(bp1 + nidx * 16 + q * 4);
                    const int chunk = nidx * 2 + (q >> 1);
                    #pragma unroll
                    for (int mt = 0; mt < 4; mt++) {
                        const int m = mt * 16 + lc;
                        s4v hv;
                        #pragma unroll
                        for (int r = 0; r < 4; r++) {
                            float v = a1[mt][j][r] + bs[r];
                            hv[r] = f2bf(v > 0.f ? v : 0.f);
                        }
                        *(s4v*)(&H1[m * 256 + ((chunk ^ (m & 7)) << 3) + ((q & 1) << 2)]) = hv;
                    }
                }
            }
            __syncthreads();

            // L2: 256 -> 256, relu
            {
                floatx4 a2[4][2];
                #pragma unroll
                for (int mt = 0; mt < 4; mt++)
                    #pragma unroll
                    for (int j = 0; j < 2; j++)
                        a2[mt][j] = (floatx4){0.f, 0.f, 0.f, 0.f};

                #pragma unroll
                for (int ks = 0; ks < 8; ks++) {
                    bf16x8 wf[2];
                    #pragma unroll
                    for (int j = 0; j < 2; j++)
                        wf[j] = *(const bf16x8*)(w2f + (((2 * w + j) * 8 + ks) << 9) + lane * 8);
                    const int c = ks * 4 + q;
                    #pragma unroll
                    for (int mt = 0; mt < 4; mt++) {
                        const int m = mt * 16 + lc;
                        bf16x8 hf = *(const bf16x8*)(&H1[m * 256 + ((c ^ (m & 7)) << 3)]);
                        #pragma unroll
                        for (int j = 0; j < 2; j++)
                            a2[mt][j] = __builtin_amdgcn_mfma_f32_16x16x32_bf16(wf[j], hf, a2[mt][j], 0, 0, 0);
                    }
                }
                __syncthreads();   // all H1 reads done before H2 write could... (H2 separate; this orders H1-reads vs next grp too)
                #pragma unroll
                for (int j = 0; j < 2; j++) {
                    const int nidx = 2 * w + j;
                    const floatx4 bs = *(const floatx4*)(bp2 + nidx * 16 + q * 4);
                    const int chunk = nidx * 2 + (q >> 1);
                    #pragma unroll
                    for (int mt = 0; mt < 4; mt++) {
                        const int m = mt * 16 + lc;
                        s4v hv;
                        #pragma unroll
                        for (int r = 0; r < 4; r++) {
                            float v = a2[mt][j][r] + bs[r];
                            hv[r] = f2bf(v > 0.f ? v : 0.f);
                        }
                        *(s4v*)(&H2[m * 256 + ((chunk ^ (m & 7)) << 3) + ((q & 1) << 2)]) = hv;
                    }
                }
            }
            __syncthreads();

            // L3: 256 -> 64 (waves 0-3; waves 4-7 join barriers only)
            {
                floatx4 a3[4];
                #pragma unroll
                for (int mt = 0; mt < 4; mt++) a3[mt] = (floatx4){0.f, 0.f, 0.f, 0.f};
                if (w < 4) {
                    #pragma unroll
                    for (int ks = 0; ks < 8; ks++) {
                        bf16x8 wf = *(const bf16x8*)(w3f + ((w * 8 + ks) << 9) + lane * 8);
                        const int c = ks * 4 + q;
                        #pragma unroll
                        for (int mt = 0; mt < 4; mt++) {
                            const int m = mt * 16 + lc;
                            bf16x8 hf = *(const bf16x8*)(&H2[m * 256 + ((c ^ (m & 7)) << 3)]);
                            a3[mt] = __builtin_amdgcn_mfma_f32_16x16x32_bf16(wf, hf, a3[mt], 0, 0, 0);
                        }
                    }
                    const floatx4 bs = *(const floatx4*)(bp3 + w * 16 + q * 4);
                    #pragma unroll
                    for (int mt = 0; mt < 4; mt++) {
                        const int m = mt * 16 + lc;
                        floatx4 hv;
                        #pragma unroll
                        for (int r = 0; r < 4; r++) hv[r] = a3[mt][r] + bs[r];
                        *(floatx4*)(&h3f[m * 68 + w * 16 + q * 4]) = hv;   // H1 free after L2
                    }
                }
            }
            __syncthreads();

            // L4: 64 -> 6, write to out at ORIGINAL point index via perm
            for (int e = tid; e < 384; e += 512) {
                int c = e >> 6, p = e & 63;
                int gp = pb2 + grp * 64 + p;
                if (gp < pend) {
                    float a = bp4[c];
                    const float* wr = wp4 + c * 64;
                    const float* xr = h3f + p * 68;
                    #pragma unroll 8
                    for (int k = 0; k < 64; k++) a += wr[k] * xr[k];
                    out[(size_t)c * NPTS + perm[gp]] = a;
                }
            }
            __syncthreads();   // h3f reads done before next grp's L1 writes H1
        }
    }
}

extern "C" void kernel_launch(void* const* d_in, const int* in_sizes, int n_in,
                              void* d_out, int out_size, void* d_ws, size_t ws_size,
                              hipStream_t stream) {
    const float* img = (const float*)d_in[0];
    const int* c0 = (const int*)d_in[1];
    const int* c1 = (const int*)d_in[2];
    const int* c2 = (const int*)d_in[3];
    const float* w_enc1 = (const float*)d_in[4];
    const float* b_enc1 = (const float*)d_in[5];
    const float* w_enc2 = (const float*)d_in[6];
    const float* b_enc2 = (const float*)d_in[7];
    const float* w_p1 = (const float*)d_in[8];
    const float* b_p1 = (const float*)d_in[9];
    const float* w_p2 = (const float*)d_in[10];
    const float* b_p2 = (const float*)d_in[11];
    const float* w_p3 = (const float*)d_in[12];
    const float* b_p3 = (const float*)d_in[13];
    const float* w_p4 = (const float*)d_in[14];
    const float* b_p4 = (const float*)d_in[15];
    float* out = (float*)d_out;

    short* f1b = (short*)d_ws;                       // 32,768,000
    short* wpb = f1b + (size_t)VOX * 64;             // 110592 (conv2 W, fragment order)
    short* w1b = wpb + 110592;                       // 16384 (MLP L1 A-frags)
    short* w2b = w1b + 16384;                        // 65536 (MLP L2 A-frags)
    short* w3b = w2b + 65536;                        // 16384 (MLP L3 A-frags)
    short* gb  = w3b + 16384;                        // 12,800,000 (unused after fusion)
    short* img_t = gb + (size_t)NPTS * 64;           // 16,384,000
    short* wc1 = img_t + (size_t)VOX * 32;           // 55296
    short* zeros = wc1 + 55296;                      // 64 shorts (128 B zero source)

    // sort arrays alias img_t (free after conv1 consumes it)
    int* perm      = (int*)img_t;                    // 200000
    int* pcoord    = perm + NPTS;                    // 200000
    int* partial   = pcoord + NPTS;                  // 32*1000  [cell][block]
    int* blockbase = partial + NSB * 1000;           // 32*1000  [cell][block]
    int* cstart    = blockbase + NSB * 1000;         // 1000
    int* cend      = cstart + 1000;                  // 1000

    hipMemsetAsync(zeros, 0, 128, stream);
    convert_weights<<<(264192 + 255) / 256, 256, 0, stream>>>(
        w_enc2, w_p1, w_p2, w_p3, w_enc1, wpb, w1b, w2b, w3b, wc1);
    transpose_img<<<(VOX + 255) / 256, 256, 0, stream>>>(img, img_t);
    conv1_mfma<<<DD * DD, 256, 0, stream>>>(img_t, wc1, b_enc1, zeros, f1b);

    // LDS-histogram counting sort into 8^3 cells
    hist_cells<<<NSB, 512, 0, stream>>>(c0, c1, c2, partial);
    scan_cells<<<1, 1024, 0, stream>>>(partial, blockbase, cstart, cend);
    scatter_points<<<NSB, 512, 0, stream>>>(c0, c1, c2, cstart, blockbase, perm, pcoord);

    conv2_mlp_fused<<<1000, 512, 0, stream>>>(
        f1b, wpb, b_enc2, cstart, cend, perm, pcoord, zeros,
        w1b, b_p1, w2b, b_p2, w3b, b_p3, w_p4, b_p4, out);
}